// Round 4
// baseline (272.695 us; speedup 1.0000x reference)
//
#include <hip/hip_runtime.h>

#define NUM_NODES 10000
#define NUM_EDGES 640000
#define D_FEAT 128

// Buckets of 16 nodes: 10000/16 = 625 exactly.
#define BSHIFT 4
#define NPB 16                        // nodes per bucket
#define NB 625                        // buckets
// Per-bucket dense segment: count ~ Binomial(640000, 1/625), mean 1024,
// sd 32. SEG_CAP = mean + 10 sigma -> P(any bucket overflows) ~ 1e-20.
// The guard below is memory-safety only (entries would be dropped with
// astronomically small probability on this fixed-seed dataset).
#define SEG_CAP 1344
#define MAXB SEG_CAP

// x in bf16: one row = 128 bf16 = 256 B = 16 uint4.
#define XB_U4 (NUM_NODES * 16)        // 160000 uint4

// K1 geometry: 625 blocks x 1024 threads = 640000 threads, 1 edge each.
#define K1_THREADS 1024

// ---------------------------------------------------------------------------
// Workspace (d_ws):
//   xb   [XB_U4]          uint4 -- x in bf16 (2.56 MB, L2/L3-resident)
//   gcur [640]            u32   -- per-bucket cursors (memset 0 each launch)
//   seg  [NB*SEG_CAP]     u32   -- dense per-bucket edge lists (3.36 MB)
// Total ~5.9 MB.
//
// Coherence note: seg lines are written by blocks on multiple XCDs, but every
// write is an atomicExch (device-coherent point) -- no partial-dirty-line
// clobber hazard (XCD L2s are not cross-coherent for plain stores). The
// K1->K2 dispatch boundary provides the release/acquire.
// ---------------------------------------------------------------------------

__device__ __forceinline__ unsigned bf16_rne(float f) {
    unsigned u = __float_as_uint(f);
    return (u + 0x7FFFu + ((u >> 16) & 1u)) >> 16;
}

// K1: fused f32->bf16 conversion + edge binning into per-bucket segments.
__global__ __launch_bounds__(K1_THREADS) void scatter_kernel(
    const int* __restrict__ ei, const float4* __restrict__ x4,
    uint4* __restrict__ xb, unsigned* __restrict__ gcur,
    unsigned* __restrict__ seg)
{
    int t = threadIdx.x, b = blockIdx.x;
    int idx = b * K1_THREADS + t;            // [0, 640000), exact cover
    int s = ei[idx];
    int d = ei[NUM_EDGES + idx];

    // bf16 conversion: first 256 threads convert this block's 256-uint4 slice
    // (625 * 256 = 160000 = XB_U4, exact cover)
    if (t < 256) {
        int o = b * 256 + t;
        float4 a = x4[2 * o];
        float4 c = x4[2 * o + 1];
        uint4 w;
        w.x = bf16_rne(a.x) | (bf16_rne(a.y) << 16);
        w.y = bf16_rne(a.z) | (bf16_rne(a.w) << 16);
        w.z = bf16_rne(c.x) | (bf16_rne(c.y) << 16);
        w.w = bf16_rne(c.z) | (bf16_rne(c.w) << 16);
        xb[o] = w;
    }

    int k = d >> BSHIFT;
    unsigned pos = atomicAdd(&gcur[k], 1u);
    if (pos < SEG_CAP)                        // safety guard only
        atomicExch(&seg[(unsigned)k * SEG_CAP + pos],
                   ((unsigned)(d & (NPB - 1)) << 16) | (unsigned)s);
}

__device__ __forceinline__ void acc8(float* a, uint4 w) {
    a[0] += __uint_as_float(w.x << 16);
    a[1] += __uint_as_float(w.x & 0xFFFF0000u);
    a[2] += __uint_as_float(w.y << 16);
    a[3] += __uint_as_float(w.y & 0xFFFF0000u);
    a[4] += __uint_as_float(w.z << 16);
    a[5] += __uint_as_float(w.z & 0xFFFF0000u);
    a[6] += __uint_as_float(w.w << 16);
    a[7] += __uint_as_float(w.w & 0xFFFF0000u);
}

__device__ __forceinline__ void reduce_write(float* a, int node, int q, int sub,
                                             float4* __restrict__ out4) {
    #pragma unroll
    for (int r = 0; r < 8; ++r) {
        a[r] += __shfl_down(a[r], 32);
        a[r] += __shfl_down(a[r], 16);
    }
    if (q == 0) {
        unsigned o = (unsigned)node * 32u + (unsigned)sub * 2u;
        out4[o]     = make_float4(a[0], a[1], a[2], a[3]);
        out4[o + 1] = make_float4(a[4], a[5], a[6], a[7]);
    }
}

// K2: per-bucket node-sort (histogram + scan + compact) + bf16 gather.
// One block per bucket; all segment entries are valid (no cell masks).
__global__ __launch_bounds__(512) void gather_kernel(
    const uint4* __restrict__ xb,            // [NUM_NODES * 16] bf16 rows
    const unsigned* __restrict__ gcur,       // [NB] bucket sizes
    const unsigned* __restrict__ seg,        // [NB*SEG_CAP] entries m<<16|src
    float4* __restrict__ out4)               // [NUM_NODES * 32]
{
    __shared__ unsigned s_src[MAXB];
    __shared__ int h[NPB];
    __shared__ int off16[NPB];
    __shared__ int cur16[NPB];

    int k = blockIdx.x;
    int t = threadIdx.x;

    if (t < NPB) h[t] = 0;
    int n = (int)min(gcur[k], (unsigned)SEG_CAP);
    __syncthreads();

    // read this bucket's dense entry list (coalesced) + histogram by node
    const unsigned* sg = seg + (unsigned)k * SEG_CAP;
    unsigned e0 = 0, e1 = 0, e2 = 0;
    bool v0 = t < n, v1 = t + 512 < n, v2 = t + 1024 < n;   // n <= 1344 < 1536
    if (v0) { e0 = sg[t];        atomicAdd(&h[e0 >> 16], 1); }
    if (v1) { e1 = sg[t + 512];  atomicAdd(&h[e1 >> 16], 1); }
    if (v2) { e2 = sg[t + 1024]; atomicAdd(&h[e2 >> 16], 1); }
    __syncthreads();

    // 16-lane shfl prefix scan (wave 0)
    if (t < NPB) {
        int v = h[t];
        int s = v;
        #pragma unroll
        for (int d = 1; d < 16; d <<= 1) {
            int u = __shfl_up(s, d, 16);
            if (t >= d) s += u;
        }
        off16[t] = s - v;
        cur16[t] = s - v;
    }
    __syncthreads();

    // compact into s_src grouped by node
    if (v0) { int p = atomicAdd(&cur16[e0 >> 16], 1); if (p < MAXB) s_src[p] = e0 & 0xFFFFu; }
    if (v1) { int p = atomicAdd(&cur16[e1 >> 16], 1); if (p < MAXB) s_src[p] = e1 & 0xFFFFu; }
    if (v2) { int p = atomicAdd(&cur16[e2 >> 16], 1); if (p < MAXB) s_src[p] = e2 & 0xFFFFu; }
    __syncthreads();

    int wave = t >> 6;          // 0..7
    int lane = t & 63;
    int q    = lane >> 4;       // which edge of the quad
    int sub  = lane & 15;       // 16 B chunk (8 bf16) within the row

    int mA = wave;              // node pair for this wave
    int mB = wave + 8;
    int begA = off16[mA], ecA = h[mA];
    int begB = off16[mB], ecB = h[mB];
    int lastA = ecA > 0 ? ecA - 1 : 0;
    int lastB = ecB > 0 ? ecB - 1 : 0;

    float aA[8] = {0.f, 0.f, 0.f, 0.f, 0.f, 0.f, 0.f, 0.f};
    float aB[8] = {0.f, 0.f, 0.f, 0.f, 0.f, 0.f, 0.f, 0.f};

    // depth-4 software pipeline: both nodes interleaved, next group prefetched
    // (clamped indices are memory-safe; invalid quads masked from accumulate)
    bool vA = q < ecA, vB = q < ecB;
    unsigned iA = (unsigned)min(begA + min(q, lastA), MAXB - 1);
    unsigned iB = (unsigned)min(begB + min(q, lastB), MAXB - 1);
    uint4 wA = xb[(s_src[iA] & 0xFFFFu) * 16u + (unsigned)sub];
    uint4 wB = xb[(s_src[iB] & 0xFFFFu) * 16u + (unsigned)sub];

    int jmax = max(ecA, ecB);
    for (int j = 0; j < jmax; j += 4) {
        int jn = j + 4;
        unsigned iA2 = (unsigned)min(begA + min(jn + q, lastA), MAXB - 1);
        unsigned iB2 = (unsigned)min(begB + min(jn + q, lastB), MAXB - 1);
        uint4 wA2 = xb[(s_src[iA2] & 0xFFFFu) * 16u + (unsigned)sub];
        uint4 wB2 = xb[(s_src[iB2] & 0xFFFFu) * 16u + (unsigned)sub];
        bool vA2 = (jn + q) < ecA;
        bool vB2 = (jn + q) < ecB;
        if (vA) acc8(aA, wA);
        if (vB) acc8(aB, wB);
        wA = wA2; vA = vA2;
        wB = wB2; vB = vB2;
    }

    reduce_write(aA, k * NPB + mA, q, sub, out4);
    reduce_write(aB, k * NPB + mB, q, sub, out4);
}

extern "C" void kernel_launch(void* const* d_in, const int* in_sizes, int n_in,
                              void* d_out, int out_size, void* d_ws, size_t ws_size,
                              hipStream_t stream) {
    const float* x   = (const float*)d_in[0];   // [10000, 128] f32
    const int*   ei  = (const int*)d_in[1];     // [2, 640000] int32
    float*       out = (float*)d_out;           // [10000, 128] f32

    uint4*    xb   = (uint4*)d_ws;                        // 2.56 MB
    unsigned* gcur = (unsigned*)(xb + XB_U4);             // 640 u32 (pad->64B)
    unsigned* seg  = gcur + 640;                          // 3.36 MB

    hipMemsetAsync(gcur, 0, NB * sizeof(unsigned), stream);

    // K1: convert x -> bf16 + bin edges into per-bucket dense segments
    scatter_kernel<<<NB, K1_THREADS, 0, stream>>>(
        ei, (const float4*)x, xb, gcur, seg);

    // K2: per-bucket histogram/scan/compact + bf16 gather reduction
    gather_kernel<<<NB, 512, 0, stream>>>(
        xb, gcur, seg, (float4*)out);
}

// Round 6
// 84.677 us; speedup vs baseline: 3.2204x; 3.2204x over previous
//
#include <hip/hip_runtime.h>

#define NUM_NODES 10000
#define NUM_EDGES 640000
#define D_FEAT 128

// Buckets of 16 nodes: 10000/16 = 625 exactly.
#define BSHIFT 4
#define NPB 16                       // nodes per bucket
#define NB 625                       // buckets
#define BLOCKS 256                   // scatter partition blocks
#define EPB (NUM_EDGES / BLOCKS)     // 2500 edges per block
// Per-(bucket,block) cell: count ~ Poisson(2500*16/10000 = 4).
// CELL_CAP=16 words = 64 B = exactly ONE cache line: single-writer per line
// (XCD-safe plain stores), no partial-line waste beyond the cell itself.
// P(cell > 16 | lam=4) ~ 4e-7; x160K cells -> ~0.06 expected overflows, which
// go to a global overflow list patched in by K2. Zero correctness risk.
// LESSON (R4): global atomicAdd binning = 195us (VALUBusy 0.2%) -- contended
// device-scope RMW serializes ~190ns/op per address. Never again.
#define CELL_CAP 16
#define MAXB 1344                    // per-bucket total bound (mean 1024, +10sd)
#define OVF_CAP 1024

// x in bf16: one row = 128 bf16 = 256 B = 16 uint4.
#define XB_U4 (NUM_NODES * 16)           // 160000 uint4
#define CVT_PER_BLOCK (XB_U4 / BLOCKS)   // 625 uint4 per block

// ---------------------------------------------------------------------------
// Workspace (d_ws):
//   xb      [XB_U4]             uint4 -- x in bf16 (2.56 MB, L2/L3-resident)
//   cnt     [BLOCKS*NB]         u32   -- cnt[b*NB+k] words in cell (0.64 MB)
//   slots   [NB*BLOCKS*CELL_CAP]u32   -- cell (k,b) at (k*256+b)*16 (10.24 MB)
//   ovf_cnt [16]                u32   -- global overflow counter (memset 0)
//   ovf     [OVF_CAP]           u32   -- overflow entries k<<18|m<<14|src
// Total ~13.5 MB.
// ---------------------------------------------------------------------------

__device__ __forceinline__ unsigned bf16_rne(float f) {
    unsigned u = __float_as_uint(f);
    return (u + 0x7FFFu + ((u >> 16) & 1u)) >> 16;
}

// K1: fused f32->bf16 conversion + scatter into private one-line cells.
// LDS cursors only (625 addresses -> low conflict); no global atomics on the
// hot path. 1024 threads = 4 waves/SIMD; ei loads hoisted to pipeline.
__global__ __launch_bounds__(1024) void scatter_cvt_kernel(
    const int* __restrict__ ei, const float4* __restrict__ x4,
    uint4* __restrict__ xb, unsigned* __restrict__ cnt,
    unsigned* __restrict__ slots, unsigned* __restrict__ ovf_cnt,
    unsigned* __restrict__ ovf)
{
    __shared__ int cur[NB];
    int t = threadIdx.x, b = blockIdx.x;
    if (t < NB) cur[t] = 0;

    // hoisted edge loads: EPB=2500 over 1024 threads = 2 full rounds + tail
    int base = b * EPB;
    int s0 = ei[base + t];
    int d0 = ei[NUM_EDGES + base + t];
    int s1 = ei[base + t + 1024];          // t+1024 <= 2047 < 2500: valid
    int d1 = ei[NUM_EDGES + base + t + 1024];
    int s2 = 0, d2 = 0;
    bool has2 = (t + 2048) < EPB;          // t < 452
    if (has2) {
        s2 = ei[base + t + 2048];
        d2 = ei[NUM_EDGES + base + t + 2048];
    }

    // fused conversion: 625 uint4 (= 5000 floats) per block, single round
    if (t < CVT_PER_BLOCK) {
        int o = b * CVT_PER_BLOCK + t;
        float4 a = x4[2 * o];
        float4 c = x4[2 * o + 1];
        uint4 w;
        w.x = bf16_rne(a.x) | (bf16_rne(a.y) << 16);
        w.y = bf16_rne(a.z) | (bf16_rne(a.w) << 16);
        w.z = bf16_rne(c.x) | (bf16_rne(c.y) << 16);
        w.w = bf16_rne(c.z) | (bf16_rne(c.w) << 16);
        xb[o] = w;
    }
    __syncthreads();   // cur[] zeroed before atomics

    {
        int k = d0 >> BSHIFT;
        int pos = atomicAdd(&cur[k], 1);
        if (pos < CELL_CAP)
            slots[(unsigned)(k * BLOCKS + b) * CELL_CAP + (unsigned)pos] =
                ((unsigned)(d0 & (NPB - 1)) << 16) | (unsigned)s0;
        else {
            unsigned g = atomicAdd(ovf_cnt, 1u);
            if (g < OVF_CAP)
                ovf[g] = ((unsigned)k << 18) |
                         ((unsigned)(d0 & (NPB - 1)) << 14) | (unsigned)s0;
        }
    }
    {
        int k = d1 >> BSHIFT;
        int pos = atomicAdd(&cur[k], 1);
        if (pos < CELL_CAP)
            slots[(unsigned)(k * BLOCKS + b) * CELL_CAP + (unsigned)pos] =
                ((unsigned)(d1 & (NPB - 1)) << 16) | (unsigned)s1;
        else {
            unsigned g = atomicAdd(ovf_cnt, 1u);
            if (g < OVF_CAP)
                ovf[g] = ((unsigned)k << 18) |
                         ((unsigned)(d1 & (NPB - 1)) << 14) | (unsigned)s1;
        }
    }
    if (has2) {
        int k = d2 >> BSHIFT;
        int pos = atomicAdd(&cur[k], 1);
        if (pos < CELL_CAP)
            slots[(unsigned)(k * BLOCKS + b) * CELL_CAP + (unsigned)pos] =
                ((unsigned)(d2 & (NPB - 1)) << 16) | (unsigned)s2;
        else {
            unsigned g = atomicAdd(ovf_cnt, 1u);
            if (g < OVF_CAP)
                ovf[g] = ((unsigned)k << 18) |
                         ((unsigned)(d2 & (NPB - 1)) << 14) | (unsigned)s2;
        }
    }
    __syncthreads();
    // coalesced per-block count row (block-private lines: XCD-safe)
    if (t < NB) cnt[b * NB + t] = (unsigned)min(cur[t], CELL_CAP);
}

__device__ __forceinline__ void acc8(float* a, uint4 w) {
    a[0] += __uint_as_float(w.x << 16);
    a[1] += __uint_as_float(w.x & 0xFFFF0000u);
    a[2] += __uint_as_float(w.y << 16);
    a[3] += __uint_as_float(w.y & 0xFFFF0000u);
    a[4] += __uint_as_float(w.z << 16);
    a[5] += __uint_as_float(w.z & 0xFFFF0000u);
    a[6] += __uint_as_float(w.w << 16);
    a[7] += __uint_as_float(w.w & 0xFFFF0000u);
}

// K2: per-bucket node-sort + bf16 gather. 1024 threads / 16 waves, ONE node
// per wave (was 2): doubles wave count (10000 waves ~ 9.8/SIMD offered) and
// removes the max(ecA,ecB) straggler. Cell read is a single coalesced
// 1024 x uint4 round (16 KB/bucket, was 40 KB).
__global__ __launch_bounds__(1024) void sort_gather_kernel(
    const uint4* __restrict__ xb,            // [NUM_NODES * 16] bf16 rows
    const unsigned* __restrict__ cnt,        // [BLOCKS*NB]
    const uint4* __restrict__ slots4,        // cells as uint4 (4 per cell)
    const unsigned* __restrict__ ovf_cnt,
    const unsigned* __restrict__ ovf,
    float4* __restrict__ out4)               // [NUM_NODES * 32]
{
    __shared__ int s_cnt[BLOCKS];
    __shared__ unsigned s_src[MAXB];
    __shared__ int h[NPB];
    __shared__ int off16[NPB];
    __shared__ int cur16[NPB];

    int k = blockIdx.x;
    int t = threadIdx.x;

    if (t < NPB) h[t] = 0;
    if (t < BLOCKS) s_cnt[t] = (int)cnt[t * NB + k];   // strided, L2-absorbed
    __syncthreads();

    // this bucket's 256 cells as 1024 uint4 (coalesced): uint4 idx t covers
    // cell c = t>>2, quarter su = t&3.
    const uint4* sb = slots4 + (unsigned)k * BLOCKS * (CELL_CAP / 4);
    uint4 w4 = sb[t];
    int v = s_cnt[t >> 2] - (t & 3) * 4;
    int vc = max(0, min(4, v));
    if (vc > 0) atomicAdd(&h[w4.x >> 16], 1);
    if (vc > 1) atomicAdd(&h[w4.y >> 16], 1);
    if (vc > 2) atomicAdd(&h[w4.z >> 16], 1);
    if (vc > 3) atomicAdd(&h[w4.w >> 16], 1);
    // overflow contributions (almost always none)
    int no = (int)min(*ovf_cnt, (unsigned)OVF_CAP);
    for (int i = t; i < no; i += 1024) {
        unsigned e = ovf[i];
        if ((int)(e >> 18) == k) atomicAdd(&h[(e >> 14) & 15u], 1);
    }
    __syncthreads();

    // 16-lane shfl prefix scan (wave 0)
    if (t < NPB) {
        int vv = h[t];
        int s = vv;
        #pragma unroll
        for (int d = 1; d < 16; d <<= 1) {
            int u = __shfl_up(s, d, 16);
            if (t >= d) s += u;
        }
        off16[t] = s - vv;
        cur16[t] = s - vv;
    }
    __syncthreads();

    // compact into s_src grouped by node
    if (vc > 0) { int p = atomicAdd(&cur16[w4.x >> 16], 1); if (p < MAXB) s_src[p] = w4.x & 0xFFFFu; }
    if (vc > 1) { int p = atomicAdd(&cur16[w4.y >> 16], 1); if (p < MAXB) s_src[p] = w4.y & 0xFFFFu; }
    if (vc > 2) { int p = atomicAdd(&cur16[w4.z >> 16], 1); if (p < MAXB) s_src[p] = w4.z & 0xFFFFu; }
    if (vc > 3) { int p = atomicAdd(&cur16[w4.w >> 16], 1); if (p < MAXB) s_src[p] = w4.w & 0xFFFFu; }
    for (int i = t; i < no; i += 1024) {
        unsigned e = ovf[i];
        if ((int)(e >> 18) == k) {
            int p = atomicAdd(&cur16[(e >> 14) & 15u], 1);
            if (p < MAXB) s_src[p] = e & 0x3FFFu;
        }
    }
    __syncthreads();

    int m    = t >> 6;          // wave -> node within bucket (0..15)
    int lane = t & 63;
    int q    = lane >> 4;       // which edge of the quad
    int sub  = lane & 15;       // 16 B chunk (8 bf16) within the row

    int beg  = off16[m], ec = h[m];
    int last = ec > 0 ? ec - 1 : 0;

    float a[8] = {0.f, 0.f, 0.f, 0.f, 0.f, 0.f, 0.f, 0.f};

    // depth-2 pipeline: group j in regs while j+4 prefetches (clamped
    // indices are memory-safe; invalid quads masked from accumulate)
    bool val = q < ec;
    unsigned i0 = (unsigned)min(beg + min(q, last), MAXB - 1);
    uint4 wv = xb[(s_src[i0] & 0xFFFFu) * 16u + (unsigned)sub];

    for (int j = 0; j < ec; j += 4) {
        int jn = j + 4;
        unsigned i1 = (unsigned)min(beg + min(jn + q, last), MAXB - 1);
        uint4 wv1 = xb[(s_src[i1] & 0xFFFFu) * 16u + (unsigned)sub];
        bool val1 = (jn + q) < ec;
        if (val) acc8(a, wv);
        wv = wv1; val = val1;
    }

    #pragma unroll
    for (int r = 0; r < 8; ++r) {
        a[r] += __shfl_down(a[r], 32);
        a[r] += __shfl_down(a[r], 16);
    }
    if (q == 0) {
        unsigned o = (unsigned)(k * NPB + m) * 32u + (unsigned)sub * 2u;
        out4[o]     = make_float4(a[0], a[1], a[2], a[3]);
        out4[o + 1] = make_float4(a[4], a[5], a[6], a[7]);
    }
}

extern "C" void kernel_launch(void* const* d_in, const int* in_sizes, int n_in,
                              void* d_out, int out_size, void* d_ws, size_t ws_size,
                              hipStream_t stream) {
    const float* x   = (const float*)d_in[0];   // [10000, 128] f32
    const int*   ei  = (const int*)d_in[1];     // [2, 640000] int32
    float*       out = (float*)d_out;           // [10000, 128] f32

    uint4*    xb      = (uint4*)d_ws;                              // 2.56 MB
    unsigned* cnt     = (unsigned*)(xb + XB_U4);                   // 0.64 MB
    unsigned* slots   = cnt + BLOCKS * NB;                         // 10.24 MB
    unsigned* ovf_cnt = slots + (size_t)NB * BLOCKS * CELL_CAP;    // 64 B
    unsigned* ovf     = ovf_cnt + 16;                              // 4 KB

    hipMemsetAsync(ovf_cnt, 0, sizeof(unsigned), stream);

    // K1: convert x -> bf16 + scatter edges into private one-line cells
    scatter_cvt_kernel<<<BLOCKS, 1024, 0, stream>>>(
        ei, (const float4*)x, xb, cnt, slots, ovf_cnt, ovf);

    // K2: per-bucket histogram/scan/compact + bf16 gather reduction
    sort_gather_kernel<<<NB, 1024, 0, stream>>>(
        xb, cnt, (const uint4*)slots, ovf_cnt, ovf, (float4*)out);
}